// Round 13
// baseline (4338.696 us; speedup 1.0000x reference)
//
#include <hip/hip_runtime.h>

// ---------------------------------------------------------------------------
// BasicBahdanauAttnDecoder: T=64 B=32 S=64 V=32000 E=512 H=512
// Round 13: r12 + register-residency for all t-invariant scan operands
// (annot/Whb/Wo held permanently; enc prefetched under B->C1 poll; xW0 under
// the end-of-step poll) + fused lse+finalize kernel. Scan runs 1 WG/CU so
// VGPRs up to the 256 cap are free.
// ---------------------------------------------------------------------------

typedef unsigned short u16;
typedef short bf16x8 __attribute__((ext_vector_type(8)));
typedef float f32x4 __attribute__((ext_vector_type(4)));

#define MFMA_BF16(a, b, c) __builtin_amdgcn_mfma_f32_16x16x32_bf16((a), (b), (c), 0, 0, 0)

struct __attribute__((aligned(8))) U16x4 { u16 x, y, z, w; };

__device__ __forceinline__ float b2f(u16 u) {
  unsigned v = ((unsigned)u) << 16; float f; __builtin_memcpy(&f, &v, 4); return f;
}
__device__ __forceinline__ u16 f2b(float f) {
  unsigned u; __builtin_memcpy(&u, &f, 4);
  u = (u + 0x7FFFu + ((u >> 16) & 1u)) >> 16;
  return (u16)u;
}
__device__ __forceinline__ float sigm(float x) { return 1.f / (1.f + __expf(-x)); }
__device__ __forceinline__ float tanh_fast(float x) {
  x = fminf(fmaxf(x, -15.f), 15.f);
  float e = __expf(2.f * x);
  return (e - 1.f) / (e + 1.f);
}

// --------- agent-scope (LLC coherence point) access helpers [sc1] ----------
__device__ __forceinline__ bf16x8 bl16(const u16* p) {
  bf16x8 v;
  asm volatile("global_load_dwordx4 %0, %1, off sc1" : "=v"(v) : "v"(p) : "memory");
  return v;
}
__device__ __forceinline__ float blf(const float* p) {
  float v;
  asm volatile("global_load_dword %0, %1, off sc1" : "=v"(v) : "v"(p) : "memory");
  return v;
}
__device__ __forceinline__ u16 blu16(const u16* p) {
  unsigned v;
  asm volatile("global_load_ushort %0, %1, off sc1" : "=v"(v) : "v"(p) : "memory");
  return (u16)v;
}
__device__ __forceinline__ void bs16(u16* p, u16 d) {
  unsigned dd = d;
  asm volatile("global_store_short %0, %1, off sc1" :: "v"(p), "v"(dd) : "memory");
}
__device__ __forceinline__ void bs32u(u16* p, unsigned d) {
  asm volatile("global_store_dword %0, %1, off sc1" :: "v"(p), "v"(d) : "memory");
}
__device__ __forceinline__ void bsf32(float* p, float d) {
  asm volatile("global_store_dword %0, %1, off sc1" :: "v"(p), "v"(d) : "memory");
}
// cached 16B load pinned at issue point (for prefetch-under-poll)
__device__ __forceinline__ bf16x8 cl16(const u16* p) {
  bf16x8 v;
  asm volatile("global_load_dwordx4 %0, %1, off" : "=v"(v) : "v"(p));
  return v;
}
__device__ __forceinline__ void vmwait() {
  asm volatile("s_waitcnt vmcnt(0)" ::: "memory");
  __builtin_amdgcn_sched_barrier(0);   // rule 18
}

// ---------------------------------------------------------------------------
// prep_all: one dispatch does zeroing + every f32->bf16 conversion + gathers.
// ---------------------------------------------------------------------------
__device__ __forceinline__ void seg_f2b4(const float* src, u16* dst, long n4,
                                         int bid, int nb) {
  long i = (long)bid * 256 + threadIdx.x;
  long stride = (long)nb * 256;
  for (; i < n4; i += stride) {
    float4 v = ((const float4*)src)[i];
    U16x4 o; o.x = f2b(v.x); o.y = f2b(v.y); o.z = f2b(v.z); o.w = f2b(v.w);
    ((U16x4*)dst)[i] = o;
  }
}
__device__ __forceinline__ void seg_strided(const float* src, u16* dst,
                                            int rows, int cols4, int sld, int soff,
                                            int dld, int doff, int bid, int nb) {
  int total = rows * cols4;
  for (int i = bid * 256 + threadIdx.x; i < total; i += nb * 256) {
    int r = i / cols4, c4 = i - r * cols4;
    float4 v = *(const float4*)(src + (size_t)r * sld + soff + c4 * 4);
    U16x4 o; o.x = f2b(v.x); o.y = f2b(v.y); o.z = f2b(v.z); o.w = f2b(v.w);
    *(U16x4*)(dst + (size_t)r * dld + doff + c4 * 4) = o;
  }
}

__global__ __launch_bounds__(256) void prep_all(
    const float* __restrict__ emb, const float* __restrict__ enc,
    const float* __restrict__ Wa, const float* __restrict__ Wh,
    const float* __restrict__ Wp, const float* __restrict__ W_ih0,
    const float* __restrict__ W_hh0, const float* __restrict__ W_ih1,
    const float* __restrict__ W_hh1, const int* __restrict__ trg,
    u16* __restrict__ emb_b, u16* __restrict__ enc_b, u16* __restrict__ Wa_b,
    u16* __restrict__ Wh_b, u16* __restrict__ Wp_b, u16* __restrict__ Wemb0_b,
    u16* __restrict__ Wcat0_b, u16* __restrict__ Wcat1_b,
    u16* __restrict__ trgemb_b, u16* __restrict__ enc_bt,
    float* __restrict__ zero_base) {
  const int bx = blockIdx.x;
  if (bx < 32) {
    for (int i = bx * 256 + threadIdx.x; i < 24832; i += 32 * 256) {
      ((float4*)zero_base)[i] = make_float4(0.f, 0.f, 0.f, 0.f);
    }
  } else if (bx < 1056) {
    seg_f2b4(emb, emb_b, 4096000, bx - 32, 1024);
  } else if (bx < 1312) {
    seg_f2b4(enc, enc_b, 524288, bx - 1056, 256);
  } else if (bx < 1376) {
    seg_f2b4(Wa, Wa_b, 131072, bx - 1312, 64);
  } else if (bx < 1408) {
    seg_f2b4(Wh, Wh_b, 65536, bx - 1376, 32);
  } else if (bx < 1536) {
    seg_f2b4(Wp, Wp_b, 196608, bx - 1408, 128);
  } else if (bx < 2048) {
    seg_strided(W_ih0, Wemb0_b, 2048, 128, 1536, 0, 512, 0, bx - 1536, 512);
  } else if (bx < 2560) {
    seg_strided(W_ih0, Wcat0_b, 2048, 256, 1536, 512, 1536, 0, bx - 2048, 512);
  } else if (bx < 3072) {
    seg_strided(W_hh0, Wcat0_b, 2048, 128, 512, 0, 1536, 1024, bx - 2560, 512);
  } else if (bx < 3584) {
    seg_strided(W_ih1, Wcat1_b, 2048, 128, 512, 0, 1024, 0, bx - 3072, 512);
  } else if (bx < 4096) {
    seg_strided(W_hh1, Wcat1_b, 2048, 128, 512, 0, 1024, 512, bx - 3584, 512);
  } else if (bx < 6144) {
    int r = bx - 4096;               // 0..2047 = t*32+b
    int v = trg[r];
    const float* srow = emb + (size_t)v * 512;
    u16* drow = trgemb_b + (size_t)r * 512;
    for (int e = threadIdx.x; e < 128; e += 256) {
      float4 x = ((const float4*)srow)[e];
      U16x4 o; o.x = f2b(x.x); o.y = f2b(x.y); o.z = f2b(x.z); o.w = f2b(x.w);
      ((U16x4*)drow)[e] = o;
    }
  } else {
    int r = bx - 6144;               // b*64+s ordering for dst
    int b = r >> 6, s = r & 63;
    const float* src = enc + (size_t)(s * 32 + b) * 1024;
    u16* dst = enc_bt + (size_t)(b * 64 + s) * 1024;
    int j = threadIdx.x;
    float4 v = ((const float4*)src)[j];
    U16x4 o; o.x = f2b(v.x); o.y = f2b(v.y); o.z = f2b(v.z); o.w = f2b(v.w);
    ((U16x4*)dst)[j] = o;
  }
}

// ---------------------------------------------------------------------------
// generic bf16 GEMM (prep GEMMs): MODE 0 f32 out, MODE 1 bf16 out,
// MODE 3 bf16 out transposed to [b][s][col] (annot_bt), rows = s*32+b, N=512.
// ---------------------------------------------------------------------------
template <int MODE>
__global__ __launch_bounds__(256) void gemm_bt(
    const u16* __restrict__ A, const u16* __restrict__ B,
    float* __restrict__ outF, u16* __restrict__ outB,
    const float* __restrict__ bias0, const float* __restrict__ bias1,
    int N, int K) {
  const int l = threadIdx.x & 63, wv = threadIdx.x >> 6;
  const int m0 = blockIdx.x * 128 + wv * 32;
  const int n0 = blockIdx.y * 64;
  const int kg = ((l >> 4) << 3);
  const u16* Ap0 = A + (size_t)(m0 + (l & 15)) * K + kg;
  const u16* Ap1 = Ap0 + (size_t)16 * K;
  const u16* Bp = B + (size_t)(n0 + (l & 15)) * K + kg;
  f32x4 acc[2][4] = {};
  for (int k0 = 0; k0 < K; k0 += 32) {
    bf16x8 a0 = *(const bf16x8*)(Ap0 + k0);
    bf16x8 a1 = *(const bf16x8*)(Ap1 + k0);
#pragma unroll
    for (int nf = 0; nf < 4; ++nf) {
      bf16x8 bb = *(const bf16x8*)(Bp + (size_t)(nf * 16) * K + k0);
      acc[0][nf] = MFMA_BF16(a0, bb, acc[0][nf]);
      acc[1][nf] = MFMA_BF16(a1, bb, acc[1][nf]);
    }
  }
  float biasv[4];
#pragma unroll
  for (int nf = 0; nf < 4; ++nf) {
    int col = n0 + nf * 16 + (l & 15);
    float bv = bias0 ? bias0[col] : 0.f;
    if (bias1) bv += bias1[col];
    biasv[nf] = bv;
  }
#pragma unroll
  for (int mi = 0; mi < 2; ++mi)
#pragma unroll
    for (int i = 0; i < 4; ++i) {
      int row = m0 + mi * 16 + ((l >> 4) << 2) + i;
#pragma unroll
      for (int nf = 0; nf < 4; ++nf) {
        int col = n0 + nf * 16 + (l & 15);
        float v = acc[mi][nf][i] + biasv[nf];
        if constexpr (MODE == 1) {
          outB[(size_t)row * N + col] = f2b(v);
        } else if constexpr (MODE == 3) {
          int b = row & 31, s = row >> 5;
          outB[(size_t)(b * 64 + s) * 512 + col] = f2b(v);
        } else {
          outF[(size_t)row * N + col] = v;
        }
      }
    }
}

// ---------------------------------------------------------------------------
// logits kernel (r9): 128x128 tiles, XCD-chunked swizzle, LDS-staged writes.
// ---------------------------------------------------------------------------
__global__ __launch_bounds__(256) void logits_kernel(
    const u16* __restrict__ A,      // pen_b [2048][512]
    const u16* __restrict__ B,      // emb_b [32000][512]
    const float* __restrict__ bias, // b_out [32000]
    float* __restrict__ out,        // [2048][32000]
    float* __restrict__ pmax, float* __restrict__ psum) {
  __shared__ float smf[128 * 132];
  const int id = blockIdx.x;
  const int lin = (id & 7) * 500 + (id >> 3);
  const int mt = lin & 15, nt = lin >> 4;
  const int gm = mt * 128, n0 = nt * 128;
  const int l = threadIdx.x & 63, wv = threadIdx.x >> 6;
  const int kg = ((l >> 4) << 3);
  const int m0 = gm + wv * 32;

  const u16* Ap0 = A + (size_t)(m0 + (l & 15)) * 512 + kg;
  const u16* Ap1 = Ap0 + (size_t)16 * 512;
  const u16* Bp = B + (size_t)(n0 + (l & 15)) * 512 + kg;
  f32x4 acc[2][8] = {};
  for (int k0 = 0; k0 < 512; k0 += 32) {
    bf16x8 a0 = *(const bf16x8*)(Ap0 + k0);
    bf16x8 a1 = *(const bf16x8*)(Ap1 + k0);
#pragma unroll
    for (int nf = 0; nf < 8; ++nf) {
      bf16x8 bb = *(const bf16x8*)(Bp + (size_t)(nf * 16) * 512 + k0);
      acc[0][nf] = MFMA_BF16(a0, bb, acc[0][nf]);
      acc[1][nf] = MFMA_BF16(a1, bb, acc[1][nf]);
    }
  }
  float bv[8];
#pragma unroll
  for (int nf = 0; nf < 8; ++nf) bv[nf] = bias[n0 + nf * 16 + (l & 15)];

  float lm[2][4], se[2][4];
#pragma unroll
  for (int mi = 0; mi < 2; ++mi)
#pragma unroll
    for (int i = 0; i < 4; ++i) {
      int rl = wv * 32 + mi * 16 + ((l >> 4) << 2) + i;
      float m_ = -3.4e38f;
#pragma unroll
      for (int nf = 0; nf < 8; ++nf) {
        float v = acc[mi][nf][i] + bv[nf];
        acc[mi][nf][i] = v;
        smf[rl * 132 + nf * 16 + (l & 15)] = v;
        m_ = fmaxf(m_, v);
      }
      lm[mi][i] = m_;
    }
#pragma unroll
  for (int d = 1; d < 16; d <<= 1)
#pragma unroll
    for (int mi = 0; mi < 2; ++mi)
#pragma unroll
      for (int i = 0; i < 4; ++i) lm[mi][i] = fmaxf(lm[mi][i], __shfl_xor(lm[mi][i], d));
#pragma unroll
  for (int mi = 0; mi < 2; ++mi)
#pragma unroll
    for (int i = 0; i < 4; ++i) {
      float s_ = 0.f;
#pragma unroll
      for (int nf = 0; nf < 8; ++nf) s_ += __expf(acc[mi][nf][i] - lm[mi][i]);
      se[mi][i] = s_;
    }
#pragma unroll
  for (int d = 1; d < 16; d <<= 1)
#pragma unroll
    for (int mi = 0; mi < 2; ++mi)
#pragma unroll
      for (int i = 0; i < 4; ++i) se[mi][i] += __shfl_xor(se[mi][i], d);
  if ((l & 15) == 0) {
#pragma unroll
    for (int mi = 0; mi < 2; ++mi)
#pragma unroll
      for (int i = 0; i < 4; ++i) {
        int row = m0 + mi * 16 + ((l >> 4) << 2) + i;
        pmax[(size_t)row * 250 + nt] = lm[mi][i];
        psum[(size_t)row * 250 + nt] = se[mi][i];
      }
  }
  __syncthreads();
#pragma unroll
  for (int r = 0; r < 128; r += 8) {
    int row = r + (threadIdx.x >> 5);
    int c4 = threadIdx.x & 31;
    float4 v = *(float4*)&smf[row * 132 + c4 * 4];
    *(float4*)&out[(size_t)(gm + row) * 32000 + n0 + c4 * 4] = v;
  }
}

__global__ __launch_bounds__(512, 2) void scan_kernel(
    const u16* __restrict__ xW0,      // [2048][2048] bf16, streamed via sc1
    const u16* __restrict__ Wcat0,    // [2048][1536]  (L2-resident)
    const u16* __restrict__ Wcat1,    // [2048][1024]  (L2-resident)
    const u16* __restrict__ Whb,      // [512][512]    (register-resident frags)
    const float* __restrict__ b_ih1, const float* __restrict__ b_hh1,
    const float* __restrict__ bh, const float* __restrict__ Wo, const float* __restrict__ bo,
    const u16* __restrict__ annot_bt, // [32][64][512] bf16 (register-resident frags)
    const u16* __restrict__ enc_bt,   // [32][64][1024] bf16 (prefetch-under-poll)
    u16* __restrict__ ctxb,           // [32][1024] bf16        (agent)
    u16* __restrict__ h0b,            // [2][32][512]           (agent)
    u16* __restrict__ h1b,            // [2][32][512]           (agent)
    float* __restrict__ c0, float* __restrict__ c1,  // WG-private (cached)
    float* __restrict__ hs,           // [32][512] f32          (agent)
    u16* __restrict__ scoresb,        // [2048][1536] bf16      (agent stores)
    float* __restrict__ dout_hc,
    unsigned* __restrict__ flags) {
  __shared__ float sm[16384];
  const int w = blockIdx.x;
  const int tid = threadIdx.x;
  const int l = tid & 63, wv = tid >> 6;
  const int jh0 = w * 16;
  const int bE = tid >> 4, jlE = tid & 15;
  const int kg = (l >> 4) << 3;
  const int sA = tid >> 3, ksA = tid & 7;   // C2 attention mapping
  unsigned phase = 0;

  float gb1[4];
#pragma unroll
  for (int g = 0; g < 4; ++g) gb1[g] = b_ih1[g * 512 + jh0 + jlE] + b_hh1[g * 512 + jh0 + jlE];
  const float bhv = bh[jh0 + jlE];
  const float bov = bo[0];
  const float wov = Wo[tid];                 // t-invariant

  // permanent register-resident operands (t-invariant):
  bf16x8 av_p[8];                            // annot fragments for C2
  {
    const u16* arow = annot_bt + (size_t)(w * 64 + sA) * 512 + ksA * 64;
#pragma unroll
    for (int kk8 = 0; kk8 < 8; ++kk8) av_p[kk8] = cl16(arow + kk8 * 8);
  }
  bf16x8 wC[2];                              // Whb fragments for C1
#pragma unroll
  for (int kk = 0; kk < 2; ++kk)
    wC[kk] = cl16(Whb + (size_t)(jh0 + (l & 15)) * 512 + wv * 64 + kk * 32 + kg);
  const u16* erow = enc_bt + (size_t)w * 65536 + tid * 2;

  // prefetch step-0 xW0
  u16 xw[4];
  {
    const u16* xp = xW0 + (size_t)(0 * 32 + bE) * 2048 + jh0 + jlE;
#pragma unroll
    for (int g = 0; g < 4; ++g) xw[g] = blu16(xp + g * 512);
  }

  for (int t = 0; t < 64; ++t) {
    const int pA = t & 1;
    // ===================== stage A: gates0 + LSTM cell 0 =====================
    {
      bf16x8 a0[6], a1[6];
#pragma unroll
      for (int kk = 0; kk < 6; ++kk) {
        const int k0 = wv * 192 + kk * 32;
        const u16* ab; int ld, off;
        if (k0 < 1024) { ab = ctxb; ld = 1024; off = k0; }
        else { ab = h0b + pA * 16384; ld = 512; off = k0 - 1024; }
        a0[kk] = bl16(ab + (size_t)(l & 15) * ld + off + kg);
        a1[kk] = bl16(ab + (size_t)((l & 15) + 16) * ld + off + kg);
      }
      vmwait();
      f32x4 acc[2][4] = {};
#pragma unroll
      for (int kk = 0; kk < 6; ++kk) {
        const int k0 = wv * 192 + kk * 32;
#pragma unroll
        for (int g = 0; g < 4; ++g) {
          bf16x8 bb = *(const bf16x8*)(Wcat0 + (size_t)(g * 512 + jh0 + (l & 15)) * 1536 + k0 + kg);
          acc[0][g] = MFMA_BF16(a0[kk], bb, acc[0][g]);
          acc[1][g] = MFMA_BF16(a1[kk], bb, acc[1][g]);
        }
      }
#pragma unroll
      for (int mi = 0; mi < 2; ++mi)
#pragma unroll
        for (int g = 0; g < 4; ++g)
#pragma unroll
          for (int i = 0; i < 4; ++i) {
            int m = mi * 16 + ((l >> 4) << 2) + i;
            sm[(wv * 32 + m) * 64 + g * 16 + (l & 15)] = acc[mi][g][i];
          }
      __syncthreads();
      {
        const int b = bE, jl = jlE, jh = jh0 + jl;
        float gate[4];
#pragma unroll
        for (int g = 0; g < 4; ++g) {
          float s = 0.f;
#pragma unroll
          for (int kv = 0; kv < 8; ++kv) s += sm[(kv * 32 + b) * 64 + g * 16 + jl];
          gate[g] = s + b2f(xw[g]);
        }
        float cn = sigm(gate[1]) * c0[b * 512 + jh] + sigm(gate[0]) * tanh_fast(gate[2]);
        float hn = sigm(gate[3]) * tanh_fast(cn);
        c0[b * 512 + jh] = cn;
        bs16(h0b + (pA ^ 1) * 16384 + b * 512 + jh, f2b(hn));
        if (t == 63) { dout_hc[b * 512 + jh] = hn; dout_hc[32768 + b * 512 + jh] = cn; }
      }
    }
    // ============ barrier A->B with Wcat1 prefetch under the poll ============
    bf16x8 wB[16];
    {
      ++phase;
      __syncthreads();
      if (tid == 0)
        __hip_atomic_store(flags + blockIdx.x * 32, phase, __ATOMIC_RELAXED,
                           __HIP_MEMORY_SCOPE_AGENT);
#pragma unroll
      for (int kk = 0; kk < 4; ++kk)
#pragma unroll
        for (int g = 0; g < 4; ++g)
          wB[kk * 4 + g] = cl16(Wcat1 + (size_t)(g * 512 + jh0 + (l & 15)) * 1024 +
                                wv * 128 + kk * 32 + kg);
      if (tid < 32) {
        int spins = 0;
        while (__hip_atomic_load(flags + tid * 32, __ATOMIC_RELAXED,
                                 __HIP_MEMORY_SCOPE_AGENT) < phase &&
               spins < 2000000) ++spins;
      }
      __syncthreads();
    }
    // ===================== stage B: gates1 + LSTM cell 1 =====================
    {
      bf16x8 a0[4], a1[4];
#pragma unroll
      for (int kk = 0; kk < 4; ++kk) {
        const int k0 = wv * 128 + kk * 32;
        const u16* ab; int off;
        if (k0 < 512) { ab = h0b + (pA ^ 1) * 16384; off = k0; }
        else { ab = h1b + pA * 16384; off = k0 - 512; }
        a0[kk] = bl16(ab + (size_t)(l & 15) * 512 + off + kg);
        a1[kk] = bl16(ab + (size_t)((l & 15) + 16) * 512 + off + kg);
      }
      vmwait();
      f32x4 acc[2][4] = {};
#pragma unroll
      for (int kk = 0; kk < 4; ++kk) {
#pragma unroll
        for (int g = 0; g < 4; ++g) {
          acc[0][g] = MFMA_BF16(a0[kk], wB[kk * 4 + g], acc[0][g]);
          acc[1][g] = MFMA_BF16(a1[kk], wB[kk * 4 + g], acc[1][g]);
        }
      }
#pragma unroll
      for (int mi = 0; mi < 2; ++mi)
#pragma unroll
        for (int g = 0; g < 4; ++g)
#pragma unroll
          for (int i = 0; i < 4; ++i) {
            int m = mi * 16 + ((l >> 4) << 2) + i;
            sm[(wv * 32 + m) * 64 + g * 16 + (l & 15)] = acc[mi][g][i];
          }
      __syncthreads();
      {
        const int b = bE, jl = jlE, jh = jh0 + jl;
        float gate[4];
#pragma unroll
        for (int g = 0; g < 4; ++g) {
          float s = 0.f;
#pragma unroll
          for (int kv = 0; kv < 8; ++kv) s += sm[(kv * 32 + b) * 64 + g * 16 + jl];
          gate[g] = s + gb1[g];
        }
        float cn = sigm(gate[1]) * c1[b * 512 + jh] + sigm(gate[0]) * tanh_fast(gate[2]);
        float hn = sigm(gate[3]) * tanh_fast(cn);
        c1[b * 512 + jh] = cn;
        u16 hb = f2b(hn);
        bs16(h1b + (pA ^ 1) * 16384 + b * 512 + jh, hb);
        bs16(scoresb + (size_t)(t * 32 + b) * 1536 + jh, hb);
        if (t == 63) { dout_hc[16384 + b * 512 + jh] = hn; dout_hc[49152 + b * 512 + jh] = cn; }
      }
    }
    // ============ barrier B->C1 with enc prefetch under the poll ============
    unsigned encv[64];
    {
      ++phase;
      __syncthreads();
      if (tid == 0)
        __hip_atomic_store(flags + blockIdx.x * 32, phase, __ATOMIC_RELAXED,
                           __HIP_MEMORY_SCOPE_AGENT);
#pragma unroll
      for (int s2 = 0; s2 < 64; ++s2)
        encv[s2] = *(const unsigned*)(erow + (size_t)s2 * 1024);
      if (tid < 32) {
        int spins = 0;
        while (__hip_atomic_load(flags + tid * 32, __ATOMIC_RELAXED,
                                 __HIP_MEMORY_SCOPE_AGENT) < phase &&
               spins < 2000000) ++spins;
      }
      __syncthreads();
    }
    // ===================== stage C1: hs = h1n @ Wh^T + bh =====================
    {
      const u16* h1n = h1b + (pA ^ 1) * 16384;
      bf16x8 a0[2], a1[2];
#pragma unroll
      for (int kk = 0; kk < 2; ++kk) {
        const int k0 = wv * 64 + kk * 32;
        a0[kk] = bl16(h1n + (size_t)(l & 15) * 512 + k0 + kg);
        a1[kk] = bl16(h1n + (size_t)((l & 15) + 16) * 512 + k0 + kg);
      }
      vmwait();
      f32x4 acc2[2] = {};
#pragma unroll
      for (int kk = 0; kk < 2; ++kk) {
        acc2[0] = MFMA_BF16(a0[kk], wC[kk], acc2[0]);
        acc2[1] = MFMA_BF16(a1[kk], wC[kk], acc2[1]);
      }
#pragma unroll
      for (int mi = 0; mi < 2; ++mi)
#pragma unroll
        for (int i = 0; i < 4; ++i)
          sm[(wv * 32 + mi * 16 + ((l >> 4) << 2) + i) * 16 + (l & 15)] = acc2[mi][i];
      __syncthreads();
      {
        const int b = bE, jl = jlE;
        float s = 0.f;
#pragma unroll
        for (int kv = 0; kv < 8; ++kv) s += sm[(kv * 32 + b) * 16 + jl];
        bsf32(hs + b * 512 + jh0 + jl, s + bhv);
      }
    }
    {
      ++phase;
      __syncthreads();
      if (tid == 0)
        __hip_atomic_store(flags + blockIdx.x * 32, phase, __ATOMIC_RELAXED,
                           __HIP_MEMORY_SCOPE_AGENT);
      if (tid < 32) {
        int spins = 0;
        while (__hip_atomic_load(flags + tid * 32, __ATOMIC_RELAXED,
                                 __HIP_MEMORY_SCOPE_AGENT) < phase &&
               spins < 2000000) ++spins;
      }
      __syncthreads();
    }
    // ========== stage C2: attention + softmax + context for batch b = w ==========
    {
      const int b = w;
      float* hs_s = sm;
      float* wo_s = sm + 512;
      float* red = sm + 1024;
      float* a_s = sm + 1536;
      float hv = blf(hs + b * 512 + tid);
      vmwait();
      hs_s[tid] = hv;
      wo_s[tid] = wov;
      __syncthreads();
      float accv = 0.f;
#pragma unroll
      for (int kk8 = 0; kk8 < 8; ++kk8) {
        bf16x8 av = av_p[kk8];
#pragma unroll
        for (int j = 0; j < 8; ++j) {
          int k = ksA * 64 + kk8 * 8 + j;
          accv += tanh_fast(hs_s[k] + b2f((u16)av[j])) * wo_s[k];
        }
      }
      red[tid] = accv;
      __syncthreads();
      if (tid < 64) {
        float e = bov;
#pragma unroll
        for (int j = 0; j < 8; ++j) e += red[tid * 8 + j];
        float mx = e;
#pragma unroll
        for (int d = 1; d < 64; d <<= 1) mx = fmaxf(mx, __shfl_xor(mx, d));
        float p = __expf(e - mx);
        float ss = p;
#pragma unroll
        for (int d = 1; d < 64; d <<= 1) ss += __shfl_xor(ss, d);
        a_s[tid] = p / ss;
      }
      __syncthreads();
      float cx0 = 0.f, cx1 = 0.f;
#pragma unroll 8
      for (int s2 = 0; s2 < 64; ++s2) {
        unsigned ev = encv[s2];
        float av = a_s[s2];
        cx0 += av * b2f((u16)(ev & 0xFFFFu));
        cx1 += av * b2f((u16)(ev >> 16));
      }
      unsigned pk = (unsigned)f2b(cx0) | ((unsigned)f2b(cx1) << 16);
      bs32u(ctxb + b * 1024 + tid * 2, pk);
      bs32u(scoresb + (size_t)(t * 32 + b) * 1536 + 512 + tid * 2, pk);
    }
    // ============ barrier C2->A with next-step xW0 prefetch under the poll ============
    {
      ++phase;
      __syncthreads();
      if (tid == 0)
        __hip_atomic_store(flags + blockIdx.x * 32, phase, __ATOMIC_RELAXED,
                           __HIP_MEMORY_SCOPE_AGENT);
      {
        const int tn = (t + 1) & 63;
        const u16* xp = xW0 + (size_t)(tn * 32 + bE) * 2048 + jh0 + jlE;
#pragma unroll
        for (int g = 0; g < 4; ++g) xw[g] = blu16(xp + g * 512);
      }
      if (tid < 32) {
        int spins = 0;
        while (__hip_atomic_load(flags + tid * 32, __ATOMIC_RELAXED,
                                 __HIP_MEMORY_SCOPE_AGENT) < phase &&
               spins < 2000000) ++spins;
      }
      __syncthreads();
    }
  }
}

// ---------------------------------------------------------------------------
// fused logsumexp combine + subtract: one block per output row.
// ---------------------------------------------------------------------------
__global__ __launch_bounds__(256) void lsefin_kernel(const float* __restrict__ pmax,
                                                     const float* __restrict__ psum,
                                                     float* __restrict__ out) {
  __shared__ float red[256];
  const int r = blockIdx.x;
  const int tid = threadIdx.x;
  float pm = (tid < 250) ? pmax[(size_t)r * 250 + tid] : -3.4e38f;
  float ps = (tid < 250) ? psum[(size_t)r * 250 + tid] : 0.f;
  red[tid] = pm; __syncthreads();
  for (int s = 128; s > 0; s >>= 1) {
    if (tid < s) red[tid] = fmaxf(red[tid], red[tid + s]);
    __syncthreads();
  }
  const float M = red[0]; __syncthreads();
  red[tid] = ps * __expf(pm - M); __syncthreads();
  for (int s = 128; s > 0; s >>= 1) {
    if (tid < s) red[tid] += red[tid + s];
    __syncthreads();
  }
  const float L = M + logf(red[0]);
  float4* rowp = (float4*)(out + (size_t)r * 32000);
  for (int i = tid; i < 8000; i += 256) {
    float4 v = rowp[i];
    v.x -= L; v.y -= L; v.z -= L; v.w -= L;
    rowp[i] = v;
  }
}

// ---------------------------------------------------------------------------
extern "C" void kernel_launch(void* const* d_in, const int* in_sizes, int n_in,
                              void* d_out, int out_size, void* d_ws, size_t ws_size,
                              hipStream_t stream) {
  const int* trg = (const int*)d_in[0];
  const float* enc = (const float*)d_in[1];
  const float* emb = (const float*)d_in[2];
  const float* W_ih0 = (const float*)d_in[3];
  const float* W_hh0 = (const float*)d_in[4];
  const float* b_ih0 = (const float*)d_in[5];
  const float* b_hh0 = (const float*)d_in[6];
  const float* W_ih1 = (const float*)d_in[7];
  const float* W_hh1 = (const float*)d_in[8];
  const float* b_ih1 = (const float*)d_in[9];
  const float* b_hh1 = (const float*)d_in[10];
  const float* Wa = (const float*)d_in[11];
  const float* ba = (const float*)d_in[12];
  const float* Wh = (const float*)d_in[13];
  const float* bh = (const float*)d_in[14];
  const float* Wo = (const float*)d_in[15];
  const float* bo = (const float*)d_in[16];
  const float* Wp = (const float*)d_in[17];
  const float* bp = (const float*)d_in[18];
  const float* b_out = (const float*)d_in[19];
  float* out = (float*)d_out;

  unsigned char* ws = (unsigned char*)d_ws;
  size_t off = 0;
  auto alloc = [&](size_t bytes) -> void* {
    void* p = ws + off; off += (bytes + 255) & ~(size_t)255; return p;
  };
  u16* emb_b = (u16*)alloc(32768000);      // [32000][512]
  u16* trgemb_b = (u16*)alloc(2097152);    // [2048][512]
  u16* enc_b = (u16*)alloc(4194304);       // [2048][1024]
  u16* Wemb0_b = (u16*)alloc(2097152);     // [2048][512]
  u16* Wcat0_b = (u16*)alloc(6291456);     // [2048][1536]
  u16* Wcat1_b = (u16*)alloc(4194304);     // [2048][1024]
  u16* Wa_b = (u16*)alloc(1048576);        // [512][1024]
  u16* Wh_b = (u16*)alloc(524288);         // [512][512]
  u16* Wp_b = (u16*)alloc(1572864);        // [512][1536]
  u16* xW0_b = (u16*)alloc(8388608);       // [2048][2048]
  u16* scoresb = (u16*)alloc(6291456);     // [2048][1536]
  u16* pen_b = (u16*)alloc(2097152);       // [2048][512]
  // --- contiguous zeroed state region (ctxb .. hsbuf + flags = 397312 B) ---
  u16* ctxb = (u16*)alloc(65536);          // [32][1024]
  u16* h0b = (u16*)alloc(65536);           // [2][32][512]
  u16* h1b = (u16*)alloc(65536);           // [2][32][512]
  float* c0 = (float*)alloc(65536);
  float* c1 = (float*)alloc(65536);
  float* hsbuf = (float*)alloc(65536);
  unsigned* flags = (unsigned*)alloc(4096);
  // -------------------------------------------------------------------------
  float* pmax = (float*)alloc(4194304);    // [2048][250] f32 (aliases annot_bt)
  float* psum = (float*)alloc(4194304);    // [2048][250] f32 (aliases enc_bt)
  if (off > ws_size) return;

  u16* annot_bt = (u16*)pmax;   // [32][64][512] bf16 = 2 MB (dead after scan)
  u16* enc_bt = (u16*)psum;     // [32][64][1024] bf16 = 4 MB (dead after scan)

  // single fused prep dispatch: zeroing + all conversions + gathers
  prep_all<<<8192, 256, 0, stream>>>(emb, enc, Wa, Wh, Wp, W_ih0, W_hh0, W_ih1, W_hh1,
                                     trg, emb_b, enc_b, Wa_b, Wh_b, Wp_b, Wemb0_b,
                                     Wcat0_b, Wcat1_b, trgemb_b, enc_bt, (float*)ctxb);

  // xW0 = trg_emb @ W_ih0[:, :512]^T + b_ih0 + b_hh0   (bf16 out)
  gemm_bt<1><<<dim3(16, 32), 256, 0, stream>>>(trgemb_b, Wemb0_b, nullptr, xW0_b,
                                               b_ih0, b_hh0, 2048, 512);
  // annot_bt[b][s][n] = bf16(enc @ Wa^T + ba)  (MODE 3: transposed bf16 out)
  gemm_bt<3><<<dim3(16, 8), 256, 0, stream>>>(enc_b, Wa_b, nullptr, annot_bt,
                                              ba, nullptr, 512, 1024);

  // recurrent scan (register-resident t-invariants + prefetch-under-poll)
  scan_kernel<<<32, 512, 0, stream>>>(xW0_b, Wcat0_b, Wcat1_b, Wh_b, b_ih1, b_hh1, bh, Wo, bo,
                                      annot_bt, enc_bt, ctxb, h0b, h1b, c0, c1, hsbuf, scoresb,
                                      out + 65536000, flags);
  // pen = stacked @ Wp^T + bp   (bf16 out)
  gemm_bt<1><<<dim3(16, 8), 256, 0, stream>>>(scoresb, Wp_b, nullptr, pen_b,
                                              bp, nullptr, 512, 1536);
  // logits = pen @ emb^T + b_out  (+ logsumexp partials), XCD-swizzled tiles
  logits_kernel<<<4000, 256, 0, stream>>>(pen_b, emb_b, b_out, out, pmax, psum);
  // fused logsumexp + subtract
  lsefin_kernel<<<2048, 256, 0, stream>>>(pmax, psum, out);
}

// Round 14
// 2348.173 us; speedup vs baseline: 1.8477x; 1.8477x over previous
//
#include <hip/hip_runtime.h>

// ---------------------------------------------------------------------------
// BasicBahdanauAttnDecoder: T=64 B=32 S=64 V=32000 E=512 H=512
// Round 14: r12 scan restored byte-for-byte (best known, 1825us) + fused
// lse+finalize tail (the only safe piece of r13). No other changes.
// ---------------------------------------------------------------------------

typedef unsigned short u16;
typedef short bf16x8 __attribute__((ext_vector_type(8)));
typedef float f32x4 __attribute__((ext_vector_type(4)));

#define MFMA_BF16(a, b, c) __builtin_amdgcn_mfma_f32_16x16x32_bf16((a), (b), (c), 0, 0, 0)

struct __attribute__((aligned(8))) U16x4 { u16 x, y, z, w; };

__device__ __forceinline__ float b2f(u16 u) {
  unsigned v = ((unsigned)u) << 16; float f; __builtin_memcpy(&f, &v, 4); return f;
}
__device__ __forceinline__ u16 f2b(float f) {
  unsigned u; __builtin_memcpy(&u, &f, 4);
  u = (u + 0x7FFFu + ((u >> 16) & 1u)) >> 16;
  return (u16)u;
}
__device__ __forceinline__ float sigm(float x) { return 1.f / (1.f + __expf(-x)); }
__device__ __forceinline__ float tanh_fast(float x) {
  x = fminf(fmaxf(x, -15.f), 15.f);
  float e = __expf(2.f * x);
  return (e - 1.f) / (e + 1.f);
}

// --------- agent-scope (LLC coherence point) access helpers [sc1] ----------
__device__ __forceinline__ bf16x8 bl16(const u16* p) {
  bf16x8 v;
  asm volatile("global_load_dwordx4 %0, %1, off sc1" : "=v"(v) : "v"(p) : "memory");
  return v;
}
__device__ __forceinline__ float blf(const float* p) {
  float v;
  asm volatile("global_load_dword %0, %1, off sc1" : "=v"(v) : "v"(p) : "memory");
  return v;
}
__device__ __forceinline__ u16 blu16(const u16* p) {
  unsigned v;
  asm volatile("global_load_ushort %0, %1, off sc1" : "=v"(v) : "v"(p) : "memory");
  return (u16)v;
}
__device__ __forceinline__ void bs16(u16* p, u16 d) {
  unsigned dd = d;
  asm volatile("global_store_short %0, %1, off sc1" :: "v"(p), "v"(dd) : "memory");
}
__device__ __forceinline__ void bs32u(u16* p, unsigned d) {
  asm volatile("global_store_dword %0, %1, off sc1" :: "v"(p), "v"(d) : "memory");
}
__device__ __forceinline__ void bsf32(float* p, float d) {
  asm volatile("global_store_dword %0, %1, off sc1" :: "v"(p), "v"(d) : "memory");
}
// cached 16B load pinned at issue point (for prefetch-under-poll)
__device__ __forceinline__ bf16x8 cl16(const u16* p) {
  bf16x8 v;
  asm volatile("global_load_dwordx4 %0, %1, off" : "=v"(v) : "v"(p));
  return v;
}
__device__ __forceinline__ void vmwait() {
  asm volatile("s_waitcnt vmcnt(0)" ::: "memory");
  __builtin_amdgcn_sched_barrier(0);   // rule 18
}

// ---------------------------------------------------------------------------
// prep_all: one dispatch does zeroing + every f32->bf16 conversion + gathers.
// ---------------------------------------------------------------------------
__device__ __forceinline__ void seg_f2b4(const float* src, u16* dst, long n4,
                                         int bid, int nb) {
  long i = (long)bid * 256 + threadIdx.x;
  long stride = (long)nb * 256;
  for (; i < n4; i += stride) {
    float4 v = ((const float4*)src)[i];
    U16x4 o; o.x = f2b(v.x); o.y = f2b(v.y); o.z = f2b(v.z); o.w = f2b(v.w);
    ((U16x4*)dst)[i] = o;
  }
}
__device__ __forceinline__ void seg_strided(const float* src, u16* dst,
                                            int rows, int cols4, int sld, int soff,
                                            int dld, int doff, int bid, int nb) {
  int total = rows * cols4;
  for (int i = bid * 256 + threadIdx.x; i < total; i += nb * 256) {
    int r = i / cols4, c4 = i - r * cols4;
    float4 v = *(const float4*)(src + (size_t)r * sld + soff + c4 * 4);
    U16x4 o; o.x = f2b(v.x); o.y = f2b(v.y); o.z = f2b(v.z); o.w = f2b(v.w);
    *(U16x4*)(dst + (size_t)r * dld + doff + c4 * 4) = o;
  }
}

__global__ __launch_bounds__(256) void prep_all(
    const float* __restrict__ emb, const float* __restrict__ enc,
    const float* __restrict__ Wa, const float* __restrict__ Wh,
    const float* __restrict__ Wp, const float* __restrict__ W_ih0,
    const float* __restrict__ W_hh0, const float* __restrict__ W_ih1,
    const float* __restrict__ W_hh1, const int* __restrict__ trg,
    u16* __restrict__ emb_b, u16* __restrict__ enc_b, u16* __restrict__ Wa_b,
    u16* __restrict__ Wh_b, u16* __restrict__ Wp_b, u16* __restrict__ Wemb0_b,
    u16* __restrict__ Wcat0_b, u16* __restrict__ Wcat1_b,
    u16* __restrict__ trgemb_b, u16* __restrict__ enc_bt,
    float* __restrict__ zero_base) {
  const int bx = blockIdx.x;
  if (bx < 32) {
    for (int i = bx * 256 + threadIdx.x; i < 24832; i += 32 * 256) {
      ((float4*)zero_base)[i] = make_float4(0.f, 0.f, 0.f, 0.f);
    }
  } else if (bx < 1056) {
    seg_f2b4(emb, emb_b, 4096000, bx - 32, 1024);
  } else if (bx < 1312) {
    seg_f2b4(enc, enc_b, 524288, bx - 1056, 256);
  } else if (bx < 1376) {
    seg_f2b4(Wa, Wa_b, 131072, bx - 1312, 64);
  } else if (bx < 1408) {
    seg_f2b4(Wh, Wh_b, 65536, bx - 1376, 32);
  } else if (bx < 1536) {
    seg_f2b4(Wp, Wp_b, 196608, bx - 1408, 128);
  } else if (bx < 2048) {
    seg_strided(W_ih0, Wemb0_b, 2048, 128, 1536, 0, 512, 0, bx - 1536, 512);
  } else if (bx < 2560) {
    seg_strided(W_ih0, Wcat0_b, 2048, 256, 1536, 512, 1536, 0, bx - 2048, 512);
  } else if (bx < 3072) {
    seg_strided(W_hh0, Wcat0_b, 2048, 128, 512, 0, 1536, 1024, bx - 2560, 512);
  } else if (bx < 3584) {
    seg_strided(W_ih1, Wcat1_b, 2048, 128, 512, 0, 1024, 0, bx - 3072, 512);
  } else if (bx < 4096) {
    seg_strided(W_hh1, Wcat1_b, 2048, 128, 512, 0, 1024, 512, bx - 3584, 512);
  } else if (bx < 6144) {
    int r = bx - 4096;               // 0..2047 = t*32+b
    int v = trg[r];
    const float* srow = emb + (size_t)v * 512;
    u16* drow = trgemb_b + (size_t)r * 512;
    for (int e = threadIdx.x; e < 128; e += 256) {
      float4 x = ((const float4*)srow)[e];
      U16x4 o; o.x = f2b(x.x); o.y = f2b(x.y); o.z = f2b(x.z); o.w = f2b(x.w);
      ((U16x4*)drow)[e] = o;
    }
  } else {
    int r = bx - 6144;               // b*64+s ordering for dst
    int b = r >> 6, s = r & 63;
    const float* src = enc + (size_t)(s * 32 + b) * 1024;
    u16* dst = enc_bt + (size_t)(b * 64 + s) * 1024;
    int j = threadIdx.x;
    float4 v = ((const float4*)src)[j];
    U16x4 o; o.x = f2b(v.x); o.y = f2b(v.y); o.z = f2b(v.z); o.w = f2b(v.w);
    ((U16x4*)dst)[j] = o;
  }
}

// ---------------------------------------------------------------------------
// generic bf16 GEMM (prep GEMMs): MODE 0 f32 out, MODE 1 bf16 out,
// MODE 3 bf16 out transposed to [b][s][col] (annot_bt), rows = s*32+b, N=512.
// ---------------------------------------------------------------------------
template <int MODE>
__global__ __launch_bounds__(256) void gemm_bt(
    const u16* __restrict__ A, const u16* __restrict__ B,
    float* __restrict__ outF, u16* __restrict__ outB,
    const float* __restrict__ bias0, const float* __restrict__ bias1,
    int N, int K) {
  const int l = threadIdx.x & 63, wv = threadIdx.x >> 6;
  const int m0 = blockIdx.x * 128 + wv * 32;
  const int n0 = blockIdx.y * 64;
  const int kg = ((l >> 4) << 3);
  const u16* Ap0 = A + (size_t)(m0 + (l & 15)) * K + kg;
  const u16* Ap1 = Ap0 + (size_t)16 * K;
  const u16* Bp = B + (size_t)(n0 + (l & 15)) * K + kg;
  f32x4 acc[2][4] = {};
  for (int k0 = 0; k0 < K; k0 += 32) {
    bf16x8 a0 = *(const bf16x8*)(Ap0 + k0);
    bf16x8 a1 = *(const bf16x8*)(Ap1 + k0);
#pragma unroll
    for (int nf = 0; nf < 4; ++nf) {
      bf16x8 bb = *(const bf16x8*)(Bp + (size_t)(nf * 16) * K + k0);
      acc[0][nf] = MFMA_BF16(a0, bb, acc[0][nf]);
      acc[1][nf] = MFMA_BF16(a1, bb, acc[1][nf]);
    }
  }
  float biasv[4];
#pragma unroll
  for (int nf = 0; nf < 4; ++nf) {
    int col = n0 + nf * 16 + (l & 15);
    float bv = bias0 ? bias0[col] : 0.f;
    if (bias1) bv += bias1[col];
    biasv[nf] = bv;
  }
#pragma unroll
  for (int mi = 0; mi < 2; ++mi)
#pragma unroll
    for (int i = 0; i < 4; ++i) {
      int row = m0 + mi * 16 + ((l >> 4) << 2) + i;
#pragma unroll
      for (int nf = 0; nf < 4; ++nf) {
        int col = n0 + nf * 16 + (l & 15);
        float v = acc[mi][nf][i] + biasv[nf];
        if constexpr (MODE == 1) {
          outB[(size_t)row * N + col] = f2b(v);
        } else if constexpr (MODE == 3) {
          int b = row & 31, s = row >> 5;
          outB[(size_t)(b * 64 + s) * 512 + col] = f2b(v);
        } else {
          outF[(size_t)row * N + col] = v;
        }
      }
    }
}

// ---------------------------------------------------------------------------
// logits kernel (r9): 128x128 tiles, XCD-chunked swizzle, LDS-staged writes.
// ---------------------------------------------------------------------------
__global__ __launch_bounds__(256) void logits_kernel(
    const u16* __restrict__ A,      // pen_b [2048][512]
    const u16* __restrict__ B,      // emb_b [32000][512]
    const float* __restrict__ bias, // b_out [32000]
    float* __restrict__ out,        // [2048][32000]
    float* __restrict__ pmax, float* __restrict__ psum) {
  __shared__ float smf[128 * 132];
  const int id = blockIdx.x;
  const int lin = (id & 7) * 500 + (id >> 3);
  const int mt = lin & 15, nt = lin >> 4;
  const int gm = mt * 128, n0 = nt * 128;
  const int l = threadIdx.x & 63, wv = threadIdx.x >> 6;
  const int kg = ((l >> 4) << 3);
  const int m0 = gm + wv * 32;

  const u16* Ap0 = A + (size_t)(m0 + (l & 15)) * 512 + kg;
  const u16* Ap1 = Ap0 + (size_t)16 * 512;
  const u16* Bp = B + (size_t)(n0 + (l & 15)) * 512 + kg;
  f32x4 acc[2][8] = {};
  for (int k0 = 0; k0 < 512; k0 += 32) {
    bf16x8 a0 = *(const bf16x8*)(Ap0 + k0);
    bf16x8 a1 = *(const bf16x8*)(Ap1 + k0);
#pragma unroll
    for (int nf = 0; nf < 8; ++nf) {
      bf16x8 bb = *(const bf16x8*)(Bp + (size_t)(nf * 16) * 512 + k0);
      acc[0][nf] = MFMA_BF16(a0, bb, acc[0][nf]);
      acc[1][nf] = MFMA_BF16(a1, bb, acc[1][nf]);
    }
  }
  float bv[8];
#pragma unroll
  for (int nf = 0; nf < 8; ++nf) bv[nf] = bias[n0 + nf * 16 + (l & 15)];

  float lm[2][4], se[2][4];
#pragma unroll
  for (int mi = 0; mi < 2; ++mi)
#pragma unroll
    for (int i = 0; i < 4; ++i) {
      int rl = wv * 32 + mi * 16 + ((l >> 4) << 2) + i;
      float m_ = -3.4e38f;
#pragma unroll
      for (int nf = 0; nf < 8; ++nf) {
        float v = acc[mi][nf][i] + bv[nf];
        acc[mi][nf][i] = v;
        smf[rl * 132 + nf * 16 + (l & 15)] = v;
        m_ = fmaxf(m_, v);
      }
      lm[mi][i] = m_;
    }
#pragma unroll
  for (int d = 1; d < 16; d <<= 1)
#pragma unroll
    for (int mi = 0; mi < 2; ++mi)
#pragma unroll
      for (int i = 0; i < 4; ++i) lm[mi][i] = fmaxf(lm[mi][i], __shfl_xor(lm[mi][i], d));
#pragma unroll
  for (int mi = 0; mi < 2; ++mi)
#pragma unroll
    for (int i = 0; i < 4; ++i) {
      float s_ = 0.f;
#pragma unroll
      for (int nf = 0; nf < 8; ++nf) s_ += __expf(acc[mi][nf][i] - lm[mi][i]);
      se[mi][i] = s_;
    }
#pragma unroll
  for (int d = 1; d < 16; d <<= 1)
#pragma unroll
    for (int mi = 0; mi < 2; ++mi)
#pragma unroll
      for (int i = 0; i < 4; ++i) se[mi][i] += __shfl_xor(se[mi][i], d);
  if ((l & 15) == 0) {
#pragma unroll
    for (int mi = 0; mi < 2; ++mi)
#pragma unroll
      for (int i = 0; i < 4; ++i) {
        int row = m0 + mi * 16 + ((l >> 4) << 2) + i;
        pmax[(size_t)row * 250 + nt] = lm[mi][i];
        psum[(size_t)row * 250 + nt] = se[mi][i];
      }
  }
  __syncthreads();
#pragma unroll
  for (int r = 0; r < 128; r += 8) {
    int row = r + (threadIdx.x >> 5);
    int c4 = threadIdx.x & 31;
    float4 v = *(float4*)&smf[row * 132 + c4 * 4];
    *(float4*)&out[(size_t)(gm + row) * 32000 + n0 + c4 * 4] = v;
  }
}

// ---------------------------------------------------------------------------
// grid barrier: RELAXED agent atomics only.
// ---------------------------------------------------------------------------
__device__ __forceinline__ void grid_barrier(unsigned* flags, unsigned phase) {
  __syncthreads();
  if (threadIdx.x == 0) {
    __hip_atomic_store(flags + blockIdx.x * 32, phase, __ATOMIC_RELAXED,
                       __HIP_MEMORY_SCOPE_AGENT);
  }
  if (threadIdx.x < 32) {
    int spins = 0;
    while (__hip_atomic_load(flags + threadIdx.x * 32, __ATOMIC_RELAXED,
                             __HIP_MEMORY_SCOPE_AGENT) < phase &&
           spins < 2000000) ++spins;
  }
  __syncthreads();
}

__global__ __launch_bounds__(512, 2) void scan_kernel(
    const u16* __restrict__ xW0,      // [2048][2048] bf16, streamed via sc1
    const u16* __restrict__ Wcat0,    // [2048][1536]  (L2-resident)
    const u16* __restrict__ Wcat1,    // [2048][1024]  (L2-resident)
    const u16* __restrict__ Whb,      // [512][512]    (L2-resident)
    const float* __restrict__ b_ih1, const float* __restrict__ b_hh1,
    const float* __restrict__ bh, const float* __restrict__ Wo, const float* __restrict__ bo,
    const u16* __restrict__ annot_bt, // [32][64][512] bf16
    const u16* __restrict__ enc_bt,   // [32][64][1024] bf16
    u16* __restrict__ ctxb,           // [32][1024] bf16        (agent)
    u16* __restrict__ h0b,            // [2][32][512]           (agent)
    u16* __restrict__ h1b,            // [2][32][512]           (agent)
    float* __restrict__ c0, float* __restrict__ c1,  // WG-private (cached)
    float* __restrict__ hs,           // [32][512] f32          (agent)
    u16* __restrict__ scoresb,        // [2048][1536] bf16      (agent stores)
    float* __restrict__ dout_hc,
    unsigned* __restrict__ flags) {
  __shared__ float sm[16384];
  const int w = blockIdx.x;
  const int tid = threadIdx.x;
  const int l = tid & 63, wv = tid >> 6;
  const int jh0 = w * 16;
  const int bE = tid >> 4, jlE = tid & 15;
  unsigned phase = 0;

  float gb1[4];
#pragma unroll
  for (int g = 0; g < 4; ++g) gb1[g] = b_ih1[g * 512 + jh0 + jlE] + b_hh1[g * 512 + jh0 + jlE];
  const float bhv = bh[jh0 + jlE];
  const float bov = bo[0];

  for (int t = 0; t < 64; ++t) {
    const int pA = t & 1;
    // ===================== stage A: gates0 + LSTM cell 0 =====================
    {
      const int kg = ((l >> 4) << 3);
      u16 xw[4];
      {
        const u16* xp = xW0 + (size_t)(t * 32 + bE) * 2048 + jh0 + jlE;
#pragma unroll
        for (int g = 0; g < 4; ++g) xw[g] = blu16(xp + g * 512);
      }
      bf16x8 a0[6], a1[6];
#pragma unroll
      for (int kk = 0; kk < 6; ++kk) {
        const int k0 = wv * 192 + kk * 32;
        const u16* ab; int ld, off;
        if (k0 < 1024) { ab = ctxb; ld = 1024; off = k0; }
        else { ab = h0b + pA * 16384; ld = 512; off = k0 - 1024; }
        a0[kk] = bl16(ab + (size_t)(l & 15) * ld + off + kg);
        a1[kk] = bl16(ab + (size_t)((l & 15) + 16) * ld + off + kg);
      }
      vmwait();
      f32x4 acc[2][4] = {};
#pragma unroll
      for (int kk = 0; kk < 6; ++kk) {
        const int k0 = wv * 192 + kk * 32;
#pragma unroll
        for (int g = 0; g < 4; ++g) {
          bf16x8 bb = *(const bf16x8*)(Wcat0 + (size_t)(g * 512 + jh0 + (l & 15)) * 1536 + k0 + kg);
          acc[0][g] = MFMA_BF16(a0[kk], bb, acc[0][g]);
          acc[1][g] = MFMA_BF16(a1[kk], bb, acc[1][g]);
        }
      }
#pragma unroll
      for (int mi = 0; mi < 2; ++mi)
#pragma unroll
        for (int g = 0; g < 4; ++g)
#pragma unroll
          for (int i = 0; i < 4; ++i) {
            int m = mi * 16 + ((l >> 4) << 2) + i;
            sm[(wv * 32 + m) * 64 + g * 16 + (l & 15)] = acc[mi][g][i];
          }
      __syncthreads();
      {
        const int b = bE, jl = jlE, jh = jh0 + jl;
        float gate[4];
#pragma unroll
        for (int g = 0; g < 4; ++g) {
          float s = 0.f;
#pragma unroll
          for (int kv = 0; kv < 8; ++kv) s += sm[(kv * 32 + b) * 64 + g * 16 + jl];
          gate[g] = s + b2f(xw[g]);
        }
        float cn = sigm(gate[1]) * c0[b * 512 + jh] + sigm(gate[0]) * tanh_fast(gate[2]);
        float hn = sigm(gate[3]) * tanh_fast(cn);
        c0[b * 512 + jh] = cn;
        bs16(h0b + (pA ^ 1) * 16384 + b * 512 + jh, f2b(hn));
        if (t == 63) { dout_hc[b * 512 + jh] = hn; dout_hc[32768 + b * 512 + jh] = cn; }
      }
    }
    // ============ barrier A->B with Wcat1 prefetch under the poll ============
    bf16x8 wB[16];
    {
      ++phase;
      __syncthreads();
      if (tid == 0)
        __hip_atomic_store(flags + blockIdx.x * 32, phase, __ATOMIC_RELAXED,
                           __HIP_MEMORY_SCOPE_AGENT);
      const int kg = ((l >> 4) << 3);
#pragma unroll
      for (int kk = 0; kk < 4; ++kk)
#pragma unroll
        for (int g = 0; g < 4; ++g)
          wB[kk * 4 + g] = cl16(Wcat1 + (size_t)(g * 512 + jh0 + (l & 15)) * 1024 +
                                wv * 128 + kk * 32 + kg);
      if (tid < 32) {
        int spins = 0;
        while (__hip_atomic_load(flags + tid * 32, __ATOMIC_RELAXED,
                                 __HIP_MEMORY_SCOPE_AGENT) < phase &&
               spins < 2000000) ++spins;
      }
      __syncthreads();
    }
    // ===================== stage B: gates1 + LSTM cell 1 =====================
    {
      const int kg = ((l >> 4) << 3);
      bf16x8 a0[4], a1[4];
#pragma unroll
      for (int kk = 0; kk < 4; ++kk) {
        const int k0 = wv * 128 + kk * 32;
        const u16* ab; int off;
        if (k0 < 512) { ab = h0b + (pA ^ 1) * 16384; off = k0; }
        else { ab = h1b + pA * 16384; off = k0 - 512; }
        a0[kk] = bl16(ab + (size_t)(l & 15) * 512 + off + kg);
        a1[kk] = bl16(ab + (size_t)((l & 15) + 16) * 512 + off + kg);
      }
      vmwait();
      f32x4 acc[2][4] = {};
#pragma unroll
      for (int kk = 0; kk < 4; ++kk) {
#pragma unroll
        for (int g = 0; g < 4; ++g) {
          acc[0][g] = MFMA_BF16(a0[kk], wB[kk * 4 + g], acc[0][g]);
          acc[1][g] = MFMA_BF16(a1[kk], wB[kk * 4 + g], acc[1][g]);
        }
      }
#pragma unroll
      for (int mi = 0; mi < 2; ++mi)
#pragma unroll
        for (int g = 0; g < 4; ++g)
#pragma unroll
          for (int i = 0; i < 4; ++i) {
            int m = mi * 16 + ((l >> 4) << 2) + i;
            sm[(wv * 32 + m) * 64 + g * 16 + (l & 15)] = acc[mi][g][i];
          }
      __syncthreads();
      {
        const int b = bE, jl = jlE, jh = jh0 + jl;
        float gate[4];
#pragma unroll
        for (int g = 0; g < 4; ++g) {
          float s = 0.f;
#pragma unroll
          for (int kv = 0; kv < 8; ++kv) s += sm[(kv * 32 + b) * 64 + g * 16 + jl];
          gate[g] = s + gb1[g];
        }
        float cn = sigm(gate[1]) * c1[b * 512 + jh] + sigm(gate[0]) * tanh_fast(gate[2]);
        float hn = sigm(gate[3]) * tanh_fast(cn);
        c1[b * 512 + jh] = cn;
        u16 hb = f2b(hn);
        bs16(h1b + (pA ^ 1) * 16384 + b * 512 + jh, hb);
        bs16(scoresb + (size_t)(t * 32 + b) * 1536 + jh, hb);
        if (t == 63) { dout_hc[16384 + b * 512 + jh] = hn; dout_hc[49152 + b * 512 + jh] = cn; }
      }
    }
    // ============ barrier B->C1 with Whb prefetch under the poll ============
    bf16x8 wC[2];
    {
      ++phase;
      __syncthreads();
      if (tid == 0)
        __hip_atomic_store(flags + blockIdx.x * 32, phase, __ATOMIC_RELAXED,
                           __HIP_MEMORY_SCOPE_AGENT);
      const int kg = ((l >> 4) << 3);
#pragma unroll
      for (int kk = 0; kk < 2; ++kk)
        wC[kk] = cl16(Whb + (size_t)(jh0 + (l & 15)) * 512 + wv * 64 + kk * 32 + kg);
      if (tid < 32) {
        int spins = 0;
        while (__hip_atomic_load(flags + tid * 32, __ATOMIC_RELAXED,
                                 __HIP_MEMORY_SCOPE_AGENT) < phase &&
               spins < 2000000) ++spins;
      }
      __syncthreads();
    }
    // ===================== stage C1: hs = h1n @ Wh^T + bh =====================
    {
      const int kg = ((l >> 4) << 3);
      const u16* h1n = h1b + (pA ^ 1) * 16384;
      bf16x8 a0[2], a1[2];
#pragma unroll
      for (int kk = 0; kk < 2; ++kk) {
        const int k0 = wv * 64 + kk * 32;
        a0[kk] = bl16(h1n + (size_t)(l & 15) * 512 + k0 + kg);
        a1[kk] = bl16(h1n + (size_t)((l & 15) + 16) * 512 + k0 + kg);
      }
      vmwait();
      f32x4 acc2[2] = {};
#pragma unroll
      for (int kk = 0; kk < 2; ++kk) {
        acc2[0] = MFMA_BF16(a0[kk], wC[kk], acc2[0]);
        acc2[1] = MFMA_BF16(a1[kk], wC[kk], acc2[1]);
      }
#pragma unroll
      for (int mi = 0; mi < 2; ++mi)
#pragma unroll
        for (int i = 0; i < 4; ++i)
          sm[(wv * 32 + mi * 16 + ((l >> 4) << 2) + i) * 16 + (l & 15)] = acc2[mi][i];
      __syncthreads();
      {
        const int b = bE, jl = jlE;
        float s = 0.f;
#pragma unroll
        for (int kv = 0; kv < 8; ++kv) s += sm[(kv * 32 + b) * 16 + jl];
        bsf32(hs + b * 512 + jh0 + jl, s + bhv);
      }
    }
    grid_barrier(flags, ++phase);
    // ========== stage C2: attention + softmax + context for batch b = w ==========
    {
      const int b = w;
      float* hs_s = sm;
      float* wo_s = sm + 512;
      float* red = sm + 1024;
      float* a_s = sm + 1536;
      float hv = blf(hs + b * 512 + tid);
      float wov = Wo[tid];
      vmwait();
      hs_s[tid] = hv;
      wo_s[tid] = wov;
      __syncthreads();
      const int s_ = tid >> 3, ks = tid & 7;
      const u16* arow = annot_bt + (size_t)(b * 64 + s_) * 512 + ks * 64;
      float accv = 0.f;
#pragma unroll
      for (int kk8 = 0; kk8 < 8; ++kk8) {
        bf16x8 av = *(const bf16x8*)(arow + kk8 * 8);
#pragma unroll
        for (int j = 0; j < 8; ++j) {
          int k = ks * 64 + kk8 * 8 + j;
          accv += tanh_fast(hs_s[k] + b2f((u16)av[j])) * wo_s[k];
        }
      }
      red[tid] = accv;
      __syncthreads();
      if (tid < 64) {
        float e = bov;
#pragma unroll
        for (int j = 0; j < 8; ++j) e += red[tid * 8 + j];
        float mx = e;
#pragma unroll
        for (int d = 1; d < 64; d <<= 1) mx = fmaxf(mx, __shfl_xor(mx, d));
        float p = __expf(e - mx);
        float ss = p;
#pragma unroll
        for (int d = 1; d < 64; d <<= 1) ss += __shfl_xor(ss, d);
        a_s[tid] = p / ss;
      }
      __syncthreads();
      float cx0 = 0.f, cx1 = 0.f;
      const u16* erow = enc_bt + (size_t)b * 65536 + tid * 2;
#pragma unroll 8
      for (int s2 = 0; s2 < 64; ++s2) {
        unsigned ev = *(const unsigned*)(erow + (size_t)s2 * 1024);
        float av = a_s[s2];
        cx0 += av * b2f((u16)(ev & 0xFFFFu));
        cx1 += av * b2f((u16)(ev >> 16));
      }
      unsigned pk = (unsigned)f2b(cx0) | ((unsigned)f2b(cx1) << 16);
      bs32u(ctxb + b * 1024 + tid * 2, pk);
      bs32u(scoresb + (size_t)(t * 32 + b) * 1536 + 512 + tid * 2, pk);
    }
    grid_barrier(flags, ++phase);
  }
}

// ---------------------------------------------------------------------------
// fused logsumexp combine + subtract: one block per output row.
// ---------------------------------------------------------------------------
__global__ __launch_bounds__(256) void lsefin_kernel(const float* __restrict__ pmax,
                                                     const float* __restrict__ psum,
                                                     float* __restrict__ out) {
  __shared__ float red[256];
  const int r = blockIdx.x;
  const int tid = threadIdx.x;
  float pm = (tid < 250) ? pmax[(size_t)r * 250 + tid] : -3.4e38f;
  float ps = (tid < 250) ? psum[(size_t)r * 250 + tid] : 0.f;
  red[tid] = pm; __syncthreads();
  for (int s = 128; s > 0; s >>= 1) {
    if (tid < s) red[tid] = fmaxf(red[tid], red[tid + s]);
    __syncthreads();
  }
  const float M = red[0]; __syncthreads();
  red[tid] = ps * __expf(pm - M); __syncthreads();
  for (int s = 128; s > 0; s >>= 1) {
    if (tid < s) red[tid] += red[tid + s];
    __syncthreads();
  }
  const float L = M + logf(red[0]);
  float4* rowp = (float4*)(out + (size_t)r * 32000);
  for (int i = tid; i < 8000; i += 256) {
    float4 v = rowp[i];
    v.x -= L; v.y -= L; v.z -= L; v.w -= L;
    rowp[i] = v;
  }
}

// ---------------------------------------------------------------------------
extern "C" void kernel_launch(void* const* d_in, const int* in_sizes, int n_in,
                              void* d_out, int out_size, void* d_ws, size_t ws_size,
                              hipStream_t stream) {
  const int* trg = (const int*)d_in[0];
  const float* enc = (const float*)d_in[1];
  const float* emb = (const float*)d_in[2];
  const float* W_ih0 = (const float*)d_in[3];
  const float* W_hh0 = (const float*)d_in[4];
  const float* b_ih0 = (const float*)d_in[5];
  const float* b_hh0 = (const float*)d_in[6];
  const float* W_ih1 = (const float*)d_in[7];
  const float* W_hh1 = (const float*)d_in[8];
  const float* b_ih1 = (const float*)d_in[9];
  const float* b_hh1 = (const float*)d_in[10];
  const float* Wa = (const float*)d_in[11];
  const float* ba = (const float*)d_in[12];
  const float* Wh = (const float*)d_in[13];
  const float* bh = (const float*)d_in[14];
  const float* Wo = (const float*)d_in[15];
  const float* bo = (const float*)d_in[16];
  const float* Wp = (const float*)d_in[17];
  const float* bp = (const float*)d_in[18];
  const float* b_out = (const float*)d_in[19];
  float* out = (float*)d_out;

  unsigned char* ws = (unsigned char*)d_ws;
  size_t off = 0;
  auto alloc = [&](size_t bytes) -> void* {
    void* p = ws + off; off += (bytes + 255) & ~(size_t)255; return p;
  };
  u16* emb_b = (u16*)alloc(32768000);      // [32000][512]
  u16* trgemb_b = (u16*)alloc(2097152);    // [2048][512]
  u16* enc_b = (u16*)alloc(4194304);       // [2048][1024]
  u16* Wemb0_b = (u16*)alloc(2097152);     // [2048][512]
  u16* Wcat0_b = (u16*)alloc(6291456);     // [2048][1536]
  u16* Wcat1_b = (u16*)alloc(4194304);     // [2048][1024]
  u16* Wa_b = (u16*)alloc(1048576);        // [512][1024]
  u16* Wh_b = (u16*)alloc(524288);         // [512][512]
  u16* Wp_b = (u16*)alloc(1572864);        // [512][1536]
  u16* xW0_b = (u16*)alloc(8388608);       // [2048][2048]
  u16* scoresb = (u16*)alloc(6291456);     // [2048][1536]
  u16* pen_b = (u16*)alloc(2097152);       // [2048][512]
  // --- contiguous zeroed state region (ctxb .. hsbuf + flags = 397312 B) ---
  u16* ctxb = (u16*)alloc(65536);          // [32][1024]
  u16* h0b = (u16*)alloc(65536);           // [2][32][512]
  u16* h1b = (u16*)alloc(65536);           // [2][32][512]
  float* c0 = (float*)alloc(65536);
  float* c1 = (float*)alloc(65536);
  float* hsbuf = (float*)alloc(65536);
  unsigned* flags = (unsigned*)alloc(4096);
  // -------------------------------------------------------------------------
  float* pmax = (float*)alloc(4194304);    // [2048][250] f32 (aliases annot_bt)
  float* psum = (float*)alloc(4194304);    // [2048][250] f32 (aliases enc_bt)
  if (off > ws_size) return;

  u16* annot_bt = (u16*)pmax;   // [32][64][512] bf16 = 2 MB (dead after scan)
  u16* enc_bt = (u16*)psum;     // [32][64][1024] bf16 = 4 MB (dead after scan)

  // single fused prep dispatch: zeroing + all conversions + gathers
  prep_all<<<8192, 256, 0, stream>>>(emb, enc, Wa, Wh, Wp, W_ih0, W_hh0, W_ih1, W_hh1,
                                     trg, emb_b, enc_b, Wa_b, Wh_b, Wp_b, Wemb0_b,
                                     Wcat0_b, Wcat1_b, trgemb_b, enc_bt, (float*)ctxb);

  // xW0 = trg_emb @ W_ih0[:, :512]^T + b_ih0 + b_hh0   (bf16 out)
  gemm_bt<1><<<dim3(16, 32), 256, 0, stream>>>(trgemb_b, Wemb0_b, nullptr, xW0_b,
                                               b_ih0, b_hh0, 2048, 512);
  // annot_bt[b][s][n] = bf16(enc @ Wa^T + ba)  (MODE 3: transposed bf16 out)
  gemm_bt<3><<<dim3(16, 8), 256, 0, stream>>>(enc_b, Wa_b, nullptr, annot_bt,
                                              ba, nullptr, 512, 1024);

  // recurrent scan (r12 structure, agent-scope state exchange)
  scan_kernel<<<32, 512, 0, stream>>>(xW0_b, Wcat0_b, Wcat1_b, Wh_b, b_ih1, b_hh1, bh, Wo, bo,
                                      annot_bt, enc_bt, ctxb, h0b, h1b, c0, c1, hsbuf, scoresb,
                                      out + 65536000, flags);
  // pen = stacked @ Wp^T + bp   (bf16 out)
  gemm_bt<1><<<dim3(16, 8), 256, 0, stream>>>(scoresb, Wp_b, nullptr, pen_b,
                                              bp, nullptr, 512, 1536);
  // logits = pen @ emb^T + b_out  (+ logsumexp partials), XCD-swizzled tiles
  logits_kernel<<<4000, 256, 0, stream>>>(pen_b, emb_b, b_out, out, pmax, psum);
  // fused logsumexp + subtract
  lsefin_kernel<<<2048, 256, 0, stream>>>(pmax, psum, out);
}